// Round 1
// baseline (108.860 us; speedup 1.0000x reference)
//
#include <hip/hip_runtime.h>
#include <hip/hip_bf16.h>

// Reference collapses to: out[i, :] = tokens[i, :] * (probs[i,0] + probs[i,1]).
// The gather/argsort/scatter_add round-trip is the identity permutation:
//   unpermuted[s] = tokens[s // top_k] for every slot s.
// Indices input is unused. Pure memory-bound elementwise scale.

#define N_TOKENS 16384
#define HIDDEN   4096
#define TOP_K    2

// HIDDEN/4 = 1024 float4 per row -> row = float4_idx >> 10
__global__ __launch_bounds__(256) void moe_scale_kernel(
    const float4* __restrict__ tokens4,
    const float*  __restrict__ probs,
    float4* __restrict__ out4)
{
    const long long total4 = (long long)N_TOKENS * (HIDDEN / 4);
    const long long stride = (long long)gridDim.x * blockDim.x;
    for (long long g = (long long)blockIdx.x * blockDim.x + threadIdx.x;
         g < total4; g += stride) {
        const int row = (int)(g >> 10);                 // HIDDEN/4 == 1024
        const float scale = probs[2 * row] + probs[2 * row + 1];
        float4 t = tokens4[g];
        t.x *= scale; t.y *= scale; t.z *= scale; t.w *= scale;
        out4[g] = t;
    }
}

extern "C" void kernel_launch(void* const* d_in, const int* in_sizes, int n_in,
                              void* d_out, int out_size, void* d_ws, size_t ws_size,
                              hipStream_t stream) {
    const float4* tokens4 = (const float4*)d_in[0];
    const float*  probs   = (const float*)d_in[1];
    // d_in[2] (indices) intentionally unused — see derivation above.
    float4* out4 = (float4*)d_out;

    const int block = 256;
    const int grid  = 2048;   // 256 CUs x 8 blocks; grid-stride covers the rest
    moe_scale_kernel<<<grid, block, 0, stream>>>(tokens4, probs, out4);
}